// Round 2
// baseline (4754.868 us; speedup 1.0000x reference)
//
#include <hip/hip_runtime.h>
#include <hip/hip_bf16.h>
#include <stdint.h>

#define DD 192
#define NSEQ 4096
#define NB 4
#define NEGV -1e9f
#define WOFF ((size_t)NB * NSEQ * DD)   // element offset of weights in d_out
#define KSPLIT 2
#define KCH (NSEQ / KSPLIT)             // 2048 k's per pv block

// ---------------------------------------------------------------------------
// World: ALL inputs fp32, d_out fp32, layout = out[4,4096,192] ++ w[4,4096,4096].
// KT (transposed K, [B][D][N]) lives in d_out[0..WOFF) until oproj overwrites.
// R4: pv is K-split 2-way; partials go to qf (dead after attn) and kf (dead
// after transpose); oproj sums the two partials during its LDS staging.
// ---------------------------------------------------------------------------

// y[r][e] = sum_d x[r][d] * W[e][d]; fp32. block 192, 8 rows/block.
__global__ __launch_bounds__(192) void proj_kernel(
        const float* __restrict__ x, const float* __restrict__ W,
        float* __restrict__ y) {
    __shared__ float xs[8][DD];
    const int r0 = blockIdx.x * 8;
    const int t  = threadIdx.x;               // 0..191 = output column e
    for (int i = t; i < 8 * DD; i += 192)
        xs[i / DD][i % DD] = x[(size_t)r0 * DD + i];
    __syncthreads();

    float acc[8] = {0.f,0.f,0.f,0.f,0.f,0.f,0.f,0.f};
    const float* wrow = W + t * DD;
    #pragma unroll
    for (int c = 0; c < DD; c += 8) {
        float4 pa = *reinterpret_cast<const float4*>(wrow + c);
        float4 pb = *reinterpret_cast<const float4*>(wrow + c + 4);
        #pragma unroll
        for (int r = 0; r < 8; ++r) {
            const float* xr = &xs[r][c];
            acc[r] += pa.x*xr[0] + pa.y*xr[1] + pa.z*xr[2] + pa.w*xr[3]
                    + pb.x*xr[4] + pb.y*xr[5] + pb.z*xr[6] + pb.w*xr[7];
        }
    }
    #pragma unroll
    for (int r = 0; r < 8; ++r) y[(size_t)(r0 + r) * DD + t] = acc[r];
}

// kf [B][N][D] -> kt [B][D][N]. 32x32 tiles via LDS.
__global__ __launch_bounds__(256) void transpose_kernel(
        const float* __restrict__ x, float* __restrict__ y) {
    __shared__ float tile[32][33];
    const int b  = blockIdx.z;
    const int n0 = blockIdx.x * 32, c0 = blockIdx.y * 32;
    const int tx = threadIdx.x, ty = threadIdx.y;
    const float* xb = x + (size_t)b * NSEQ * DD;
    #pragma unroll
    for (int i = ty; i < 32; i += 8)
        tile[i][tx] = xb[(size_t)(n0 + i) * DD + c0 + tx];
    __syncthreads();
    float* yb = y + (size_t)b * DD * NSEQ;
    #pragma unroll
    for (int j = ty; j < 32; j += 8)
        yb[(size_t)(c0 + j) * NSEQ + n0 + tx] = tile[tx][j];
}

// logits = q k^T + bias + mask*NEG; softmax rows; fp32 weights to d_out+WOFF.
// grid (NSEQ/8, NB), block 512 (8 waves). 8 q-rows per block.
__global__ __launch_bounds__(512, 4) void attn_softmax_kernel(
        const float* __restrict__ qws, const float* __restrict__ kt,
        const float* __restrict__ bias, const float* __restrict__ mask,
        float* __restrict__ dout) {
    const int b  = blockIdx.y;
    const int q0 = blockIdx.x * 8;
    const int t  = threadIdx.x;               // 0..511
    const int t4 = t << 2;

    __shared__ float qs[8][DD];               // 6 KB
    for (int i = t; i < 8 * DD; i += 512) {
        int r = i / DD, d = i % DD;
        qs[r][d] = qws[((size_t)(b * NSEQ + q0 + r)) * DD + d];
    }
    __syncthreads();

    float acc[8][8];
    #pragma unroll
    for (int r = 0; r < 8; ++r)
        #pragma unroll
        for (int j = 0; j < 8; ++j) acc[r][j] = 0.f;

    const float* ktb = kt + (size_t)b * DD * NSEQ;
    for (int c0 = 0; c0 < DD; c0 += 2) {
        float2 q2[8];
        #pragma unroll
        for (int r = 0; r < 8; ++r)
            q2[r] = *reinterpret_cast<const float2*>(&qs[r][c0]);   // wave-broadcast
        #pragma unroll
        for (int cc = 0; cc < 2; ++cc) {
            const float* ktc = ktb + (size_t)(c0 + cc) * NSEQ;
            const float4 k0 = *reinterpret_cast<const float4*>(ktc + t4);
            const float4 k1 = *reinterpret_cast<const float4*>(ktc + 2048 + t4);
            #pragma unroll
            for (int r = 0; r < 8; ++r) {
                const float qc = (cc == 0) ? q2[r].x : q2[r].y;
                acc[r][0] += qc * k0.x; acc[r][1] += qc * k0.y;
                acc[r][2] += qc * k0.z; acc[r][3] += qc * k0.w;
                acc[r][4] += qc * k1.x; acc[r][5] += qc * k1.y;
                acc[r][6] += qc * k1.z; acc[r][7] += qc * k1.w;
            }
        }
    }

    const int lane = t & 63, wid = t >> 6;    // 8 waves
    __shared__ float red[8][8];
    float pm[8];
    #pragma unroll
    for (int r = 0; r < 8; ++r) {
        const size_t rowoff = ((size_t)(b * NSEQ + q0 + r)) * NSEQ;
        const float4 b0 = *reinterpret_cast<const float4*>(&bias[rowoff + t4]);
        const float4 b1 = *reinterpret_cast<const float4*>(&bias[rowoff + 2048 + t4]);
        const float4 m0 = *reinterpret_cast<const float4*>(&mask[rowoff + t4]);
        const float4 m1 = *reinterpret_cast<const float4*>(&mask[rowoff + 2048 + t4]);
        acc[r][0] += b0.x + m0.x * NEGV;
        acc[r][1] += b0.y + m0.y * NEGV;
        acc[r][2] += b0.z + m0.z * NEGV;
        acc[r][3] += b0.w + m0.w * NEGV;
        acc[r][4] += b1.x + m1.x * NEGV;
        acc[r][5] += b1.y + m1.y * NEGV;
        acc[r][6] += b1.z + m1.z * NEGV;
        acc[r][7] += b1.w + m1.w * NEGV;
        float m = acc[r][0];
        #pragma unroll
        for (int j = 1; j < 8; ++j) m = fmaxf(m, acc[r][j]);
        pm[r] = m;
    }
    #pragma unroll
    for (int r = 0; r < 8; ++r) {
        float m = pm[r];
        #pragma unroll
        for (int off = 32; off; off >>= 1) m = fmaxf(m, __shfl_down(m, off));
        if (lane == 0) red[r][wid] = m;
    }
    __syncthreads();
    float rowmax[8];
    #pragma unroll
    for (int r = 0; r < 8; ++r) {
        float m = red[r][0];
        #pragma unroll
        for (int w = 1; w < 8; ++w) m = fmaxf(m, red[r][w]);
        rowmax[r] = m;
    }
    float psum[8];
    #pragma unroll
    for (int r = 0; r < 8; ++r) {
        float s = 0.f;
        #pragma unroll
        for (int j = 0; j < 8; ++j) {
            float e = __expf(acc[r][j] - rowmax[r]);
            acc[r][j] = e;
            s += e;
        }
        psum[r] = s;
    }
    __syncthreads();   // done reading red (maxes) before overwrite
    #pragma unroll
    for (int r = 0; r < 8; ++r) {
        float s = psum[r];
        #pragma unroll
        for (int off = 32; off; off >>= 1) s += __shfl_down(s, off);
        if (lane == 0) red[r][wid] = s;
    }
    __syncthreads();
    float* wout = dout + WOFF;
    #pragma unroll
    for (int r = 0; r < 8; ++r) {
        float s = red[r][0];
        #pragma unroll
        for (int w = 1; w < 8; ++w) s += red[r][w];
        const float inv = 1.0f / s;
        const size_t rowoff = ((size_t)(b * NSEQ + q0 + r)) * NSEQ;
        const float4 o0 = make_float4(acc[r][0] * inv, acc[r][1] * inv,
                                      acc[r][2] * inv, acc[r][3] * inv);
        const float4 o1 = make_float4(acc[r][4] * inv, acc[r][5] * inv,
                                      acc[r][6] * inv, acc[r][7] * inv);
        *reinterpret_cast<float4*>(&wout[rowoff + t4]) = o0;
        *reinterpret_cast<float4*>(&wout[rowoff + 2048 + t4]) = o1;
    }
}

// part[kz][q][e] = sum_{k in kz range} w[q][k] * v[k][e].
// grid (NSEQ/8, NB, KSPLIT), block 64 (1 wave). Thread: e in {t,t+64,t+128},
// 8 q-rows. V double-buffered in registers to hide load latency.
__global__ __launch_bounds__(64, 4) void pv_kernel(
        const float* __restrict__ dout, const float* __restrict__ vws,
        float* __restrict__ part) {
    const int b  = blockIdx.y;
    const int q0 = blockIdx.x * 8;
    const int kz = blockIdx.z;
    const int t  = threadIdx.x;

    __shared__ float wsh[8][256];   // 8 KB
    float acc[8][3];
    #pragma unroll
    for (int r = 0; r < 8; ++r) { acc[r][0] = 0.f; acc[r][1] = 0.f; acc[r][2] = 0.f; }

    const float* wts = dout + WOFF;
    const float* vbp = vws + (size_t)b * NSEQ * DD;

    auto loadV = [&](float vv[8][3], int kbase) {
        #pragma unroll
        for (int i = 0; i < 8; ++i) {
            const float* vrow = &vbp[(size_t)(kbase + i) * DD];
            vv[i][0] = vrow[t]; vv[i][1] = vrow[t + 64]; vv[i][2] = vrow[t + 128];
        }
    };
    auto fmastep = [&](int kk, const float vv[8][3]) {
        #pragma unroll
        for (int r = 0; r < 8; ++r) {
            float4 pa = *reinterpret_cast<const float4*>(&wsh[r][kk]);
            float4 pb = *reinterpret_cast<const float4*>(&wsh[r][kk + 4]);
            #pragma unroll
            for (int e = 0; e < 3; ++e) {
                acc[r][e] += pa.x * vv[0][e] + pa.y * vv[1][e] + pa.z * vv[2][e] + pa.w * vv[3][e]
                           + pb.x * vv[4][e] + pb.y * vv[5][e] + pb.z * vv[6][e] + pb.w * vv[7][e];
            }
        }
    };

    const int kbeg = kz * KCH;
    for (int k0 = kbeg; k0 < kbeg + KCH; k0 += 256) {
        __syncthreads();
        // stage W[8][256] via float4: 512 float4 over 64 threads
        for (int i = t; i < 512; i += 64) {
            const int r = i >> 6, c4 = (i & 63) << 2;
            *reinterpret_cast<float4*>(&wsh[r][c4]) =
                *reinterpret_cast<const float4*>(&wts[((size_t)(b * NSEQ + q0 + r)) * NSEQ + k0 + c4]);
        }
        __syncthreads();

        float va[8][3], vb2[8][3];
        loadV(va, k0);
        for (int kk = 0; kk < 256; kk += 16) {
            loadV(vb2, k0 + kk + 8);
            fmastep(kk, va);
            if (kk + 16 < 256) loadV(va, k0 + kk + 16);
            fmastep(kk + 8, vb2);
        }
    }

    float* po = part + (size_t)kz * (size_t)NB * NSEQ * DD;
    #pragma unroll
    for (int r = 0; r < 8; ++r) {
        float* mrow = &po[((size_t)(b * NSEQ + q0 + r)) * DD];
        mrow[t] = acc[r][0]; mrow[t + 64] = acc[r][1]; mrow[t + 128] = acc[r][2];
    }
}

// final[r][o] = sum_e (p0+p1)[r][e] * OW[o][e]; fp32 out to d_out[0..].
// K-split reduction folded into the LDS staging.
__global__ __launch_bounds__(192) void oproj_kernel(
        const float* __restrict__ p0, const float* __restrict__ p1,
        const float* __restrict__ W, float* __restrict__ y) {
    __shared__ float xs[8][DD];
    const int r0 = blockIdx.x * 8;
    const int t  = threadIdx.x;
    for (int i = t; i < 8 * DD; i += 192)
        xs[i / DD][i % DD] = p0[(size_t)r0 * DD + i] + p1[(size_t)r0 * DD + i];
    __syncthreads();

    float acc[8] = {0.f,0.f,0.f,0.f,0.f,0.f,0.f,0.f};
    const float* wrow = W + t * DD;
    #pragma unroll
    for (int c = 0; c < DD; c += 8) {
        float4 pa = *reinterpret_cast<const float4*>(wrow + c);
        float4 pb = *reinterpret_cast<const float4*>(wrow + c + 4);
        #pragma unroll
        for (int r = 0; r < 8; ++r) {
            const float* xr = &xs[r][c];
            acc[r] += pa.x*xr[0] + pa.y*xr[1] + pa.z*xr[2] + pa.w*xr[3]
                    + pb.x*xr[4] + pb.y*xr[5] + pb.z*xr[6] + pb.w*xr[7];
        }
    }
    #pragma unroll
    for (int r = 0; r < 8; ++r) y[(size_t)(r0 + r) * DD + t] = acc[r];
}

extern "C" void kernel_launch(void* const* d_in, const int* in_sizes, int n_in,
                              void* d_out, int out_size, void* d_ws, size_t ws_size,
                              hipStream_t stream) {
    const float* query = (const float*)d_in[0];
    const float* key   = (const float*)d_in[1];
    const float* value = (const float*)d_in[2];
    const float* mask  = (const float*)d_in[3];
    const float* bias  = (const float*)d_in[4];
    const float* qw    = (const float*)d_in[5];
    const float* kw    = (const float*)d_in[6];
    const float* vw    = (const float*)d_in[7];
    const float* ow    = (const float*)d_in[8];

    const size_t nrows = (size_t)NB * NSEQ;   // 16384
    float* dout = (float*)d_out;

    // workspace: q | k | v fp32 (37.75 MB).
    // After attn, qf is dead; after transpose, kf is dead.
    // pv partials: part0 = qf region, part1 = kf region (contiguous).
    float* qf  = (float*)d_ws;
    float* kf  = qf + nrows * DD;
    float* vf  = kf + nrows * DD;
    float* part = qf;          // part + kz*nrows*DD, kz in {0,1}

    // KT[b][c][n] scratch in d_out[0..WOFF): dead once attn completes;
    // oproj (last kernel) overwrites that region with the real output.
    float* ktp = dout;

    proj_kernel<<<dim3(nrows / 8), 192, 0, stream>>>(query, qw, qf);
    proj_kernel<<<dim3(nrows / 8), 192, 0, stream>>>(key,   kw, kf);
    proj_kernel<<<dim3(nrows / 8), 192, 0, stream>>>(value, vw, vf);

    transpose_kernel<<<dim3(NSEQ / 32, DD / 32, NB), dim3(32, 8), 0, stream>>>(kf, ktp);

    attn_softmax_kernel<<<dim3(NSEQ / 8, NB), 512, 0, stream>>>(
        qf, ktp, bias, mask, dout);

    pv_kernel<<<dim3(NSEQ / 8, NB, KSPLIT), 64, 0, stream>>>(dout, vf, part);

    oproj_kernel<<<dim3(nrows / 8), 192, 0, stream>>>(
        part, part + nrows * (size_t)DD, ow, dout);
}

// Round 3
// 4717.983 us; speedup vs baseline: 1.0078x; 1.0078x over previous
//
#include <hip/hip_runtime.h>
#include <hip/hip_bf16.h>
#include <stdint.h>

#define DD 192
#define NSEQ 4096
#define NB 4
#define NEGV -1e9f
#define WOFF ((size_t)NB * NSEQ * DD)   // element offset of weights in d_out
#define KSPLIT 2
#define KCH (NSEQ / KSPLIT)             // 2048 k's per pvo block

// ---------------------------------------------------------------------------
// World: ALL inputs fp32, d_out fp32, layout = out[4,4096,192] ++ w[4,4096,4096].
// Fusion (R2): out = W @ (value @ (Ow·Vw)^T)  — oproj and mid eliminated.
//   M  = Ow·Vw        lives in d_out+WOFF (weights region, dead until attn)
//   KT = K^T [B][D][N] lives in d_out[0..WOFF) (out region, dead until addout)
//   vo = value @ M^T   lives in vf workspace region
//   pvo partials       live in qf/kf regions (dead after attn/transpose)
// R2 lesson: NO lambdas taking array params in hot loops (pointer decay ->
// scratch, 9 GB spill traffic in R1). All hot arrays unrolled-const-indexed.
// ---------------------------------------------------------------------------

// y[r][e] = sum_d x[r][d] * W[e][d]; fp32. block 192, 8 rows/block.
__global__ __launch_bounds__(192) void proj_kernel(
        const float* __restrict__ x, const float* __restrict__ W,
        float* __restrict__ y) {
    __shared__ float xs[8][DD];
    const int r0 = blockIdx.x * 8;
    const int t  = threadIdx.x;               // 0..191 = output column e
    for (int i = t; i < 8 * DD; i += 192)
        xs[i / DD][i % DD] = x[(size_t)r0 * DD + i];
    __syncthreads();

    float acc[8] = {0.f,0.f,0.f,0.f,0.f,0.f,0.f,0.f};
    const float* wrow = W + t * DD;
    #pragma unroll
    for (int c = 0; c < DD; c += 8) {
        float4 pa = *reinterpret_cast<const float4*>(wrow + c);
        float4 pb = *reinterpret_cast<const float4*>(wrow + c + 4);
        #pragma unroll
        for (int r = 0; r < 8; ++r) {
            const float* xr = &xs[r][c];
            acc[r] += pa.x*xr[0] + pa.y*xr[1] + pa.z*xr[2] + pa.w*xr[3]
                    + pb.x*xr[4] + pb.y*xr[5] + pb.z*xr[6] + pb.w*xr[7];
        }
    }
    #pragma unroll
    for (int r = 0; r < 8; ++r) y[(size_t)(r0 + r) * DD + t] = acc[r];
}

// M[o][d] = sum_e ow[o][e] * vw[e][d]. grid 192, block 192. Tiny.
__global__ __launch_bounds__(192) void wcomp_kernel(
        const float* __restrict__ ow, const float* __restrict__ vw,
        float* __restrict__ M) {
    __shared__ float os[DD];
    const int o = blockIdx.x, t = threadIdx.x;
    os[t] = ow[o * DD + t];
    __syncthreads();
    float acc = 0.f;
    for (int e = 0; e < DD; ++e) acc += os[e] * vw[e * DD + t];
    M[o * DD + t] = acc;
}

// kf [B][N][D] -> kt [B][D][N]. 32x32 tiles via LDS.
__global__ __launch_bounds__(256) void transpose_kernel(
        const float* __restrict__ x, float* __restrict__ y) {
    __shared__ float tile[32][33];
    const int b  = blockIdx.z;
    const int n0 = blockIdx.x * 32, c0 = blockIdx.y * 32;
    const int tx = threadIdx.x, ty = threadIdx.y;
    const float* xb = x + (size_t)b * NSEQ * DD;
    #pragma unroll
    for (int i = ty; i < 32; i += 8)
        tile[i][tx] = xb[(size_t)(n0 + i) * DD + c0 + tx];
    __syncthreads();
    float* yb = y + (size_t)b * DD * NSEQ;
    #pragma unroll
    for (int j = ty; j < 32; j += 8)
        yb[(size_t)(c0 + j) * NSEQ + n0 + tx] = tile[tx][j];
}

// logits = q k^T + bias + mask*NEG; softmax rows; fp32 weights to d_out+WOFF.
// grid (NSEQ/8, NB), block 512 (8 waves). 8 q-rows per block.
__global__ __launch_bounds__(512, 4) void attn_softmax_kernel(
        const float* __restrict__ qws, const float* __restrict__ kt,
        const float* __restrict__ bias, const float* __restrict__ mask,
        float* __restrict__ dout) {
    const int b  = blockIdx.y;
    const int q0 = blockIdx.x * 8;
    const int t  = threadIdx.x;               // 0..511
    const int t4 = t << 2;

    __shared__ float qs[8][DD];               // 6 KB
    for (int i = t; i < 8 * DD; i += 512) {
        int r = i / DD, d = i % DD;
        qs[r][d] = qws[((size_t)(b * NSEQ + q0 + r)) * DD + d];
    }
    __syncthreads();

    float acc[8][8];
    #pragma unroll
    for (int r = 0; r < 8; ++r)
        #pragma unroll
        for (int j = 0; j < 8; ++j) acc[r][j] = 0.f;

    const float* ktb = kt + (size_t)b * DD * NSEQ;
    for (int c0 = 0; c0 < DD; c0 += 2) {
        float2 q2[8];
        #pragma unroll
        for (int r = 0; r < 8; ++r)
            q2[r] = *reinterpret_cast<const float2*>(&qs[r][c0]);   // wave-broadcast
        #pragma unroll
        for (int cc = 0; cc < 2; ++cc) {
            const float* ktc = ktb + (size_t)(c0 + cc) * NSEQ;
            const float4 k0 = *reinterpret_cast<const float4*>(ktc + t4);
            const float4 k1 = *reinterpret_cast<const float4*>(ktc + 2048 + t4);
            #pragma unroll
            for (int r = 0; r < 8; ++r) {
                const float qc = (cc == 0) ? q2[r].x : q2[r].y;
                acc[r][0] += qc * k0.x; acc[r][1] += qc * k0.y;
                acc[r][2] += qc * k0.z; acc[r][3] += qc * k0.w;
                acc[r][4] += qc * k1.x; acc[r][5] += qc * k1.y;
                acc[r][6] += qc * k1.z; acc[r][7] += qc * k1.w;
            }
        }
    }

    const int lane = t & 63, wid = t >> 6;    // 8 waves
    __shared__ float red[8][8];
    float pm[8];
    #pragma unroll
    for (int r = 0; r < 8; ++r) {
        const size_t rowoff = ((size_t)(b * NSEQ + q0 + r)) * NSEQ;
        const float4 b0 = *reinterpret_cast<const float4*>(&bias[rowoff + t4]);
        const float4 b1 = *reinterpret_cast<const float4*>(&bias[rowoff + 2048 + t4]);
        const float4 m0 = *reinterpret_cast<const float4*>(&mask[rowoff + t4]);
        const float4 m1 = *reinterpret_cast<const float4*>(&mask[rowoff + 2048 + t4]);
        acc[r][0] += b0.x + m0.x * NEGV;
        acc[r][1] += b0.y + m0.y * NEGV;
        acc[r][2] += b0.z + m0.z * NEGV;
        acc[r][3] += b0.w + m0.w * NEGV;
        acc[r][4] += b1.x + m1.x * NEGV;
        acc[r][5] += b1.y + m1.y * NEGV;
        acc[r][6] += b1.z + m1.z * NEGV;
        acc[r][7] += b1.w + m1.w * NEGV;
        float m = acc[r][0];
        #pragma unroll
        for (int j = 1; j < 8; ++j) m = fmaxf(m, acc[r][j]);
        pm[r] = m;
    }
    #pragma unroll
    for (int r = 0; r < 8; ++r) {
        float m = pm[r];
        #pragma unroll
        for (int off = 32; off; off >>= 1) m = fmaxf(m, __shfl_down(m, off));
        if (lane == 0) red[r][wid] = m;
    }
    __syncthreads();
    float rowmax[8];
    #pragma unroll
    for (int r = 0; r < 8; ++r) {
        float m = red[r][0];
        #pragma unroll
        for (int w = 1; w < 8; ++w) m = fmaxf(m, red[r][w]);
        rowmax[r] = m;
    }
    float psum[8];
    #pragma unroll
    for (int r = 0; r < 8; ++r) {
        float s = 0.f;
        #pragma unroll
        for (int j = 0; j < 8; ++j) {
            float e = __expf(acc[r][j] - rowmax[r]);
            acc[r][j] = e;
            s += e;
        }
        psum[r] = s;
    }
    __syncthreads();   // done reading red (maxes) before overwrite
    #pragma unroll
    for (int r = 0; r < 8; ++r) {
        float s = psum[r];
        #pragma unroll
        for (int off = 32; off; off >>= 1) s += __shfl_down(s, off);
        if (lane == 0) red[r][wid] = s;
    }
    __syncthreads();
    float* wout = dout + WOFF;
    #pragma unroll
    for (int r = 0; r < 8; ++r) {
        float s = red[r][0];
        #pragma unroll
        for (int w = 1; w < 8; ++w) s += red[r][w];
        const float inv = 1.0f / s;
        const size_t rowoff = ((size_t)(b * NSEQ + q0 + r)) * NSEQ;
        const float4 o0 = make_float4(acc[r][0] * inv, acc[r][1] * inv,
                                      acc[r][2] * inv, acc[r][3] * inv);
        const float4 o1 = make_float4(acc[r][4] * inv, acc[r][5] * inv,
                                      acc[r][6] * inv, acc[r][7] * inv);
        *reinterpret_cast<float4*>(&wout[rowoff + t4]) = o0;
        *reinterpret_cast<float4*>(&wout[rowoff + 2048 + t4]) = o1;
    }
}

// part[kz][q][o] = sum_{k in kz half} w[q][k] * vo[k][o].
// grid (NSEQ/32, NB, KSPLIT) = 1024 blocks (exactly 4/CU), block 256 (4 waves).
// Wave wid owns q-rows q0+8*wid..+7; lane owns o in {lane, lane+64, lane+128}.
// W tile 32x256 staged in LDS (broadcast reads, conflict-free); V loads are
// identical across the 4 waves -> L1 reuse. V register-double-buffered,
// everything inline + unrolled (NO array-pointer escapes -> no scratch).
__global__ __launch_bounds__(256, 4) void pvo_kernel(
        const float* __restrict__ dout, const float* __restrict__ vo,
        float* __restrict__ part) {
    const int b    = blockIdx.y;
    const int q0   = blockIdx.x * 32;
    const int kz   = blockIdx.z;
    const int t    = threadIdx.x;
    const int lane = t & 63, wid = t >> 6;

    __shared__ float wsh[32][256];           // 32 KB

    float acc[8][3];
    #pragma unroll
    for (int r = 0; r < 8; ++r) {
        acc[r][0] = 0.f; acc[r][1] = 0.f; acc[r][2] = 0.f;
    }

    const float* wts   = dout + WOFF;
    const float* vbase = vo + (size_t)b * NSEQ * DD + lane;
    const int kbeg = kz * KCH;

    float va[8][3], vb[8][3];

    for (int k0 = kbeg; k0 < kbeg + KCH; k0 += 256) {
        __syncthreads();
        #pragma unroll
        for (int i = 0; i < 8; ++i) {        // stage W[32][256], fully coalesced
            const int idx = t + i * 256;
            const int r = idx >> 6, c4 = (idx & 63) << 2;
            *reinterpret_cast<float4*>(&wsh[r][c4]) =
                *reinterpret_cast<const float4*>(
                    &wts[((size_t)(b * NSEQ + q0 + r)) * NSEQ + k0 + c4]);
        }
        __syncthreads();

        const float* vr = vbase + (size_t)k0 * DD;
        #pragma unroll
        for (int i = 0; i < 8; ++i) {
            va[i][0] = vr[0]; va[i][1] = vr[64]; va[i][2] = vr[128];
            vr += DD;
        }
        for (int kk = 0; kk < 256; kk += 16) {
            #pragma unroll
            for (int i = 0; i < 8; ++i) {
                vb[i][0] = vr[0]; vb[i][1] = vr[64]; vb[i][2] = vr[128];
                vr += DD;
            }
            #pragma unroll
            for (int r = 0; r < 8; ++r) {
                const float4 pa = *reinterpret_cast<const float4*>(&wsh[wid * 8 + r][kk]);
                const float4 pb = *reinterpret_cast<const float4*>(&wsh[wid * 8 + r][kk + 4]);
                #pragma unroll
                for (int e = 0; e < 3; ++e) {
                    acc[r][e] += pa.x * va[0][e] + pa.y * va[1][e]
                               + pa.z * va[2][e] + pa.w * va[3][e]
                               + pb.x * va[4][e] + pb.y * va[5][e]
                               + pb.z * va[6][e] + pb.w * va[7][e];
                }
            }
            if (kk + 16 < 256) {
                #pragma unroll
                for (int i = 0; i < 8; ++i) {
                    va[i][0] = vr[0]; va[i][1] = vr[64]; va[i][2] = vr[128];
                    vr += DD;
                }
            }
            #pragma unroll
            for (int r = 0; r < 8; ++r) {
                const float4 pa = *reinterpret_cast<const float4*>(&wsh[wid * 8 + r][kk + 8]);
                const float4 pb = *reinterpret_cast<const float4*>(&wsh[wid * 8 + r][kk + 12]);
                #pragma unroll
                for (int e = 0; e < 3; ++e) {
                    acc[r][e] += pa.x * vb[0][e] + pa.y * vb[1][e]
                               + pa.z * vb[2][e] + pa.w * vb[3][e]
                               + pb.x * vb[4][e] + pb.y * vb[5][e]
                               + pb.z * vb[6][e] + pb.w * vb[7][e];
                }
            }
        }
    }

    float* po = part + (size_t)kz * ((size_t)NB * NSEQ * DD);
    #pragma unroll
    for (int r = 0; r < 8; ++r) {
        float* mrow = &po[((size_t)(b * NSEQ + q0 + wid * 8 + r)) * DD + lane];
        mrow[0] = acc[r][0]; mrow[64] = acc[r][1]; mrow[128] = acc[r][2];
    }
}

// final out = p0 + p1 (K-split reduction), float4, fully coalesced.
__global__ __launch_bounds__(256) void addout_kernel(
        const float* __restrict__ p0, const float* __restrict__ p1,
        float* __restrict__ y) {
    const size_t i = ((size_t)blockIdx.x * 256 + threadIdx.x) * 4;
    const float4 a = *reinterpret_cast<const float4*>(p0 + i);
    const float4 b = *reinterpret_cast<const float4*>(p1 + i);
    float4 c;
    c.x = a.x + b.x; c.y = a.y + b.y; c.z = a.z + b.z; c.w = a.w + b.w;
    *reinterpret_cast<float4*>(y + i) = c;
}

extern "C" void kernel_launch(void* const* d_in, const int* in_sizes, int n_in,
                              void* d_out, int out_size, void* d_ws, size_t ws_size,
                              hipStream_t stream) {
    const float* query = (const float*)d_in[0];
    const float* key   = (const float*)d_in[1];
    const float* value = (const float*)d_in[2];
    const float* mask  = (const float*)d_in[3];
    const float* bias  = (const float*)d_in[4];
    const float* qw    = (const float*)d_in[5];
    const float* kw    = (const float*)d_in[6];
    const float* vw    = (const float*)d_in[7];
    const float* ow    = (const float*)d_in[8];

    const size_t nrows = (size_t)NB * NSEQ;   // 16384
    float* dout = (float*)d_out;

    // workspace: qf | kf | vf (37.75 MB).
    // qf dead after attn, kf dead after transpose -> pvo partials live there.
    float* qf   = (float*)d_ws;
    float* kf   = qf + nrows * DD;
    float* vf   = kf + nrows * DD;            // holds vo = value @ M^T
    float* part = qf;                          // part + kz*nrows*DD, kz in {0,1}

    // Scratch in d_out:
    //   KT [B][D][N] in d_out[0..WOFF)  — dead after attn, overwritten by addout
    //   M  [192][192] at d_out+WOFF     — dead after vo-proj, overwritten by attn
    float* ktp = dout;
    float* Mw  = dout + WOFF;

    wcomp_kernel<<<dim3(DD), 192, 0, stream>>>(ow, vw, Mw);

    proj_kernel<<<dim3(nrows / 8), 192, 0, stream>>>(query, qw, qf);
    proj_kernel<<<dim3(nrows / 8), 192, 0, stream>>>(key,   kw, kf);
    proj_kernel<<<dim3(nrows / 8), 192, 0, stream>>>(value, Mw, vf);

    transpose_kernel<<<dim3(NSEQ / 32, DD / 32, NB), dim3(32, 8), 0, stream>>>(kf, ktp);

    attn_softmax_kernel<<<dim3(NSEQ / 8, NB), 512, 0, stream>>>(
        qf, ktp, bias, mask, dout);

    pvo_kernel<<<dim3(NSEQ / 32, NB, KSPLIT), 256, 0, stream>>>(dout, vf, part);

    addout_kernel<<<dim3((nrows * DD) / 1024), 256, 0, stream>>>(
        part, part + nrows * DD, dout);
}

// Round 4
// 1610.596 us; speedup vs baseline: 2.9522x; 2.9293x over previous
//
#include <hip/hip_runtime.h>
#include <hip/hip_bf16.h>
#include <stdint.h>

#define DD 192
#define NSEQ 4096
#define NB 4
#define NEGV -1e9f
#define WOFF ((size_t)NB * NSEQ * DD)   // element offset of weights in d_out
#define KSPLIT 2
#define KCH (NSEQ / KSPLIT)             // 2048 k's per pvo block

// ---------------------------------------------------------------------------
// World: ALL inputs fp32, d_out fp32, layout = out[4,4096,192] ++ w[4,4096,4096].
// Fusion: out = W @ (value @ (Ow·Vw)^T)  — oproj and mid eliminated.
//   M  = Ow·Vw        lives in d_out+WOFF (weights region, dead until attn)
//   KT = K^T [B][D][N] lives in d_out[0..WOFF) (out region, dead until addout)
//   vo = value @ M^T   lives in vf workspace region
//   pvo partials       live in qf/kf regions (dead after attn/transpose)
// SPILL LESSON (R1+R2): per-thread arrays must be declared AND consumed inside
// one unrolled loop body. Any array live across a non-unrolled loop iteration
// (double-buffer pattern) gets demoted to scratch (7.7 GB spill traffic, 4x
// slowdown). No lambdas with array params. No conditional refills.
// ---------------------------------------------------------------------------

// y[r][e] = sum_d x[r][d] * W[e][d]; fp32. block 192, 8 rows/block.
__global__ __launch_bounds__(192) void proj_kernel(
        const float* __restrict__ x, const float* __restrict__ W,
        float* __restrict__ y) {
    __shared__ float xs[8][DD];
    const int r0 = blockIdx.x * 8;
    const int t  = threadIdx.x;               // 0..191 = output column e
    for (int i = t; i < 8 * DD; i += 192)
        xs[i / DD][i % DD] = x[(size_t)r0 * DD + i];
    __syncthreads();

    float acc[8] = {0.f,0.f,0.f,0.f,0.f,0.f,0.f,0.f};
    const float* wrow = W + t * DD;
    #pragma unroll
    for (int c = 0; c < DD; c += 8) {
        float4 pa = *reinterpret_cast<const float4*>(wrow + c);
        float4 pb = *reinterpret_cast<const float4*>(wrow + c + 4);
        #pragma unroll
        for (int r = 0; r < 8; ++r) {
            const float* xr = &xs[r][c];
            acc[r] += pa.x*xr[0] + pa.y*xr[1] + pa.z*xr[2] + pa.w*xr[3]
                    + pb.x*xr[4] + pb.y*xr[5] + pb.z*xr[6] + pb.w*xr[7];
        }
    }
    #pragma unroll
    for (int r = 0; r < 8; ++r) y[(size_t)(r0 + r) * DD + t] = acc[r];
}

// M[o][d] = sum_e ow[o][e] * vw[e][d]. grid 192, block 192. Tiny.
__global__ __launch_bounds__(192) void wcomp_kernel(
        const float* __restrict__ ow, const float* __restrict__ vw,
        float* __restrict__ M) {
    __shared__ float os[DD];
    const int o = blockIdx.x, t = threadIdx.x;
    os[t] = ow[o * DD + t];
    __syncthreads();
    float acc = 0.f;
    for (int e = 0; e < DD; ++e) acc += os[e] * vw[e * DD + t];
    M[o * DD + t] = acc;
}

// kf [B][N][D] -> kt [B][D][N]. 32x32 tiles via LDS.
__global__ __launch_bounds__(256) void transpose_kernel(
        const float* __restrict__ x, float* __restrict__ y) {
    __shared__ float tile[32][33];
    const int b  = blockIdx.z;
    const int n0 = blockIdx.x * 32, c0 = blockIdx.y * 32;
    const int tx = threadIdx.x, ty = threadIdx.y;
    const float* xb = x + (size_t)b * NSEQ * DD;
    #pragma unroll
    for (int i = ty; i < 32; i += 8)
        tile[i][tx] = xb[(size_t)(n0 + i) * DD + c0 + tx];
    __syncthreads();
    float* yb = y + (size_t)b * DD * NSEQ;
    #pragma unroll
    for (int j = ty; j < 32; j += 8)
        yb[(size_t)(c0 + j) * NSEQ + n0 + tx] = tile[tx][j];
}

// logits = q k^T + bias + mask*NEG; softmax rows; fp32 weights to d_out+WOFF.
// grid (NSEQ/8, NB), block 512 (8 waves). 8 q-rows per block.
__global__ __launch_bounds__(512, 4) void attn_softmax_kernel(
        const float* __restrict__ qws, const float* __restrict__ kt,
        const float* __restrict__ bias, const float* __restrict__ mask,
        float* __restrict__ dout) {
    const int b  = blockIdx.y;
    const int q0 = blockIdx.x * 8;
    const int t  = threadIdx.x;               // 0..511
    const int t4 = t << 2;

    __shared__ float qs[8][DD];               // 6 KB
    for (int i = t; i < 8 * DD; i += 512) {
        int r = i / DD, d = i % DD;
        qs[r][d] = qws[((size_t)(b * NSEQ + q0 + r)) * DD + d];
    }
    __syncthreads();

    float acc[8][8];
    #pragma unroll
    for (int r = 0; r < 8; ++r)
        #pragma unroll
        for (int j = 0; j < 8; ++j) acc[r][j] = 0.f;

    const float* ktb = kt + (size_t)b * DD * NSEQ;
    for (int c0 = 0; c0 < DD; c0 += 2) {
        float2 q2[8];
        #pragma unroll
        for (int r = 0; r < 8; ++r)
            q2[r] = *reinterpret_cast<const float2*>(&qs[r][c0]);   // wave-broadcast
        #pragma unroll
        for (int cc = 0; cc < 2; ++cc) {
            const float* ktc = ktb + (size_t)(c0 + cc) * NSEQ;
            const float4 k0 = *reinterpret_cast<const float4*>(ktc + t4);
            const float4 k1 = *reinterpret_cast<const float4*>(ktc + 2048 + t4);
            #pragma unroll
            for (int r = 0; r < 8; ++r) {
                const float qc = (cc == 0) ? q2[r].x : q2[r].y;
                acc[r][0] += qc * k0.x; acc[r][1] += qc * k0.y;
                acc[r][2] += qc * k0.z; acc[r][3] += qc * k0.w;
                acc[r][4] += qc * k1.x; acc[r][5] += qc * k1.y;
                acc[r][6] += qc * k1.z; acc[r][7] += qc * k1.w;
            }
        }
    }

    const int lane = t & 63, wid = t >> 6;    // 8 waves
    __shared__ float red[8][8];
    float pm[8];
    #pragma unroll
    for (int r = 0; r < 8; ++r) {
        const size_t rowoff = ((size_t)(b * NSEQ + q0 + r)) * NSEQ;
        const float4 b0 = *reinterpret_cast<const float4*>(&bias[rowoff + t4]);
        const float4 b1 = *reinterpret_cast<const float4*>(&bias[rowoff + 2048 + t4]);
        const float4 m0 = *reinterpret_cast<const float4*>(&mask[rowoff + t4]);
        const float4 m1 = *reinterpret_cast<const float4*>(&mask[rowoff + 2048 + t4]);
        acc[r][0] += b0.x + m0.x * NEGV;
        acc[r][1] += b0.y + m0.y * NEGV;
        acc[r][2] += b0.z + m0.z * NEGV;
        acc[r][3] += b0.w + m0.w * NEGV;
        acc[r][4] += b1.x + m1.x * NEGV;
        acc[r][5] += b1.y + m1.y * NEGV;
        acc[r][6] += b1.z + m1.z * NEGV;
        acc[r][7] += b1.w + m1.w * NEGV;
        float m = acc[r][0];
        #pragma unroll
        for (int j = 1; j < 8; ++j) m = fmaxf(m, acc[r][j]);
        pm[r] = m;
    }
    #pragma unroll
    for (int r = 0; r < 8; ++r) {
        float m = pm[r];
        #pragma unroll
        for (int off = 32; off; off >>= 1) m = fmaxf(m, __shfl_down(m, off));
        if (lane == 0) red[r][wid] = m;
    }
    __syncthreads();
    float rowmax[8];
    #pragma unroll
    for (int r = 0; r < 8; ++r) {
        float m = red[r][0];
        #pragma unroll
        for (int w = 1; w < 8; ++w) m = fmaxf(m, red[r][w]);
        rowmax[r] = m;
    }
    float psum[8];
    #pragma unroll
    for (int r = 0; r < 8; ++r) {
        float s = 0.f;
        #pragma unroll
        for (int j = 0; j < 8; ++j) {
            float e = __expf(acc[r][j] - rowmax[r]);
            acc[r][j] = e;
            s += e;
        }
        psum[r] = s;
    }
    __syncthreads();   // done reading red (maxes) before overwrite
    #pragma unroll
    for (int r = 0; r < 8; ++r) {
        float s = psum[r];
        #pragma unroll
        for (int off = 32; off; off >>= 1) s += __shfl_down(s, off);
        if (lane == 0) red[r][wid] = s;
    }
    __syncthreads();
    float* wout = dout + WOFF;
    #pragma unroll
    for (int r = 0; r < 8; ++r) {
        float s = red[r][0];
        #pragma unroll
        for (int w = 1; w < 8; ++w) s += red[r][w];
        const float inv = 1.0f / s;
        const size_t rowoff = ((size_t)(b * NSEQ + q0 + r)) * NSEQ;
        const float4 o0 = make_float4(acc[r][0] * inv, acc[r][1] * inv,
                                      acc[r][2] * inv, acc[r][3] * inv);
        const float4 o1 = make_float4(acc[r][4] * inv, acc[r][5] * inv,
                                      acc[r][6] * inv, acc[r][7] * inv);
        *reinterpret_cast<float4*>(&wout[rowoff + t4]) = o0;
        *reinterpret_cast<float4*>(&wout[rowoff + 2048 + t4]) = o1;
    }
}

// part[kz][q][o] = sum_{k in kz half} w[q][k] * vo[k][o].
// grid (NSEQ/32, NB, KSPLIT) = 1024 blocks (exactly 4/CU), block 256 (4 waves).
// Wave wid owns q-rows q0+8*wid..+7; lane owns o in {lane, lane+64, lane+128}.
// W tile 32x256 in LDS (broadcast reads, conflict-free). V loads identical
// across the 4 waves -> L1 reuse; latency hidden by TLP (4 waves/SIMD), NOT
// by source-level double-buffering (that spills — see header comment).
// V regs (v0/v1/v2) are born and die inside one unrolled kk step.
__global__ __launch_bounds__(256, 4) void pvo_kernel(
        const float* __restrict__ dout, const float* __restrict__ vo,
        float* __restrict__ part) {
    const int b    = blockIdx.y;
    const int q0   = blockIdx.x * 32;
    const int kz   = blockIdx.z;
    const int t    = threadIdx.x;
    const int lane = t & 63, wid = t >> 6;

    __shared__ float wsh[32][256];           // 32 KB

    float acc[8][3];
    #pragma unroll
    for (int r = 0; r < 8; ++r) {
        acc[r][0] = 0.f; acc[r][1] = 0.f; acc[r][2] = 0.f;
    }

    const float* wts   = dout + WOFF;
    const float* vbase = vo + (size_t)b * NSEQ * DD + lane;
    const int kbeg = kz * KCH;

    for (int k0 = kbeg; k0 < kbeg + KCH; k0 += 256) {
        __syncthreads();
        #pragma unroll
        for (int i = 0; i < 8; ++i) {        // stage W[32][256], fully coalesced
            const int idx = t + i * 256;
            const int r = idx >> 6, c4 = (idx & 63) << 2;
            *reinterpret_cast<float4*>(&wsh[r][c4]) =
                *reinterpret_cast<const float4*>(
                    &wts[((size_t)(b * NSEQ + q0 + r)) * NSEQ + k0 + c4]);
        }
        __syncthreads();

        const float* vr = vbase + (size_t)k0 * DD;
        for (int kk = 0; kk < 256; kk += 8) {
            float v0[8], v1[8], v2[8];       // live only within this step
            #pragma unroll
            for (int i = 0; i < 8; ++i) {
                v0[i] = vr[0]; v1[i] = vr[64]; v2[i] = vr[128];
                vr += DD;
            }
            #pragma unroll
            for (int r = 0; r < 8; ++r) {
                const float4 pa = *reinterpret_cast<const float4*>(&wsh[wid * 8 + r][kk]);
                const float4 pb = *reinterpret_cast<const float4*>(&wsh[wid * 8 + r][kk + 4]);
                acc[r][0] += pa.x * v0[0] + pa.y * v0[1] + pa.z * v0[2] + pa.w * v0[3]
                           + pb.x * v0[4] + pb.y * v0[5] + pb.z * v0[6] + pb.w * v0[7];
                acc[r][1] += pa.x * v1[0] + pa.y * v1[1] + pa.z * v1[2] + pa.w * v1[3]
                           + pb.x * v1[4] + pb.y * v1[5] + pb.z * v1[6] + pb.w * v1[7];
                acc[r][2] += pa.x * v2[0] + pa.y * v2[1] + pa.z * v2[2] + pa.w * v2[3]
                           + pb.x * v2[4] + pb.y * v2[5] + pb.z * v2[6] + pb.w * v2[7];
            }
        }
    }

    float* po = part + (size_t)kz * ((size_t)NB * NSEQ * DD);
    #pragma unroll
    for (int r = 0; r < 8; ++r) {
        float* mrow = &po[((size_t)(b * NSEQ + q0 + wid * 8 + r)) * DD + lane];
        mrow[0] = acc[r][0]; mrow[64] = acc[r][1]; mrow[128] = acc[r][2];
    }
}

// final out = p0 + p1 (K-split reduction), float4, fully coalesced.
__global__ __launch_bounds__(256) void addout_kernel(
        const float* __restrict__ p0, const float* __restrict__ p1,
        float* __restrict__ y) {
    const size_t i = ((size_t)blockIdx.x * 256 + threadIdx.x) * 4;
    const float4 a = *reinterpret_cast<const float4*>(p0 + i);
    const float4 b = *reinterpret_cast<const float4*>(p1 + i);
    float4 c;
    c.x = a.x + b.x; c.y = a.y + b.y; c.z = a.z + b.z; c.w = a.w + b.w;
    *reinterpret_cast<float4*>(y + i) = c;
}

extern "C" void kernel_launch(void* const* d_in, const int* in_sizes, int n_in,
                              void* d_out, int out_size, void* d_ws, size_t ws_size,
                              hipStream_t stream) {
    const float* query = (const float*)d_in[0];
    const float* key   = (const float*)d_in[1];
    const float* value = (const float*)d_in[2];
    const float* mask  = (const float*)d_in[3];
    const float* bias  = (const float*)d_in[4];
    const float* qw    = (const float*)d_in[5];
    const float* kw    = (const float*)d_in[6];
    const float* vw    = (const float*)d_in[7];
    const float* ow    = (const float*)d_in[8];

    const size_t nrows = (size_t)NB * NSEQ;   // 16384
    float* dout = (float*)d_out;

    // workspace: qf | kf | vf (37.75 MB).
    // qf dead after attn, kf dead after transpose -> pvo partials live there.
    float* qf   = (float*)d_ws;
    float* kf   = qf + nrows * DD;
    float* vf   = kf + nrows * DD;            // holds vo = value @ M^T
    float* part = qf;                          // part + kz*nrows*DD, kz in {0,1}

    // Scratch in d_out:
    //   KT [B][D][N] in d_out[0..WOFF)  — dead after attn, overwritten by addout
    //   M  [192][192] at d_out+WOFF     — dead after vo-proj, overwritten by attn
    float* ktp = dout;
    float* Mw  = dout + WOFF;

    wcomp_kernel<<<dim3(DD), 192, 0, stream>>>(ow, vw, Mw);

    proj_kernel<<<dim3(nrows / 8), 192, 0, stream>>>(query, qw, qf);
    proj_kernel<<<dim3(nrows / 8), 192, 0, stream>>>(key,   kw, kf);
    proj_kernel<<<dim3(nrows / 8), 192, 0, stream>>>(value, Mw, vf);

    transpose_kernel<<<dim3(NSEQ / 32, DD / 32, NB), dim3(32, 8), 0, stream>>>(kf, ktp);

    attn_softmax_kernel<<<dim3(NSEQ / 8, NB), 512, 0, stream>>>(
        qf, ktp, bias, mask, dout);

    pvo_kernel<<<dim3(NSEQ / 32, NB, KSPLIT), 256, 0, stream>>>(dout, vf, part);

    addout_kernel<<<dim3((nrows * DD) / 1024), 256, 0, stream>>>(
        part, part + nrows * DD, dout);
}